// Round 3
// baseline (12887.231 us; speedup 1.0000x reference)
//
#include <hip/hip_runtime.h>
#include <stdint.h>

#define Bb 64
#define Tt 512
#define Ii 1024
#define Uu 1024
#define KK 2048
#define NN 3072
#define TC 128            // scan chunk length
#define NCHUNK 4
#define NBLK 256

typedef __attribute__((ext_vector_type(8))) short short8;
typedef __attribute__((ext_vector_type(4))) float f32x4;
typedef __attribute__((ext_vector_type(4))) unsigned short us4;

__device__ __forceinline__ unsigned short f2bf(float f) {
    union { float f; unsigned u; } v; v.f = f;
    return (unsigned short)((v.u + 0x7FFFu + ((v.u >> 16) & 1u)) >> 16);
}
__device__ __forceinline__ float bf2f(unsigned short h) {
    union { unsigned u; float f; } v; v.u = ((unsigned)h) << 16;
    return v.f;
}

__device__ __forceinline__ float2 block_reduce2(float s, float s2) {
    int lane = threadIdx.x & 63, wv = threadIdx.x >> 6;
    #pragma unroll
    for (int m = 32; m > 0; m >>= 1) {
        s  += __shfl_down(s,  m, 64);
        s2 += __shfl_down(s2, m, 64);
    }
    __shared__ float sh[4][2];
    if (lane == 0) { sh[wv][0] = s; sh[wv][1] = s2; }
    __syncthreads();
    float a = 0.f, b = 0.f;
    if (threadIdx.x == 0) {
        #pragma unroll
        for (int i = 0; i < 4; ++i) { a += sh[i][0]; b += sh[i][1]; }
    }
    return make_float2(a, b);
}

// W (3072x2048 f32) -> Wc, Wx (bf16, LN-scale folded), S_n, bias2_n
__global__ __launch_bounds__(256) void k_prep_w(
        const float* __restrict__ W, const float* __restrict__ bvec,
        const float* __restrict__ lns, const float* __restrict__ lnb,
        unsigned short* __restrict__ Wc, unsigned short* __restrict__ Wx,
        float* __restrict__ S, float* __restrict__ bias2) {
    int n = blockIdx.x;
    const float* wr = W + (size_t)n * KK;
    float s = 0.f, bb = 0.f;
    for (int j = threadIdx.x; j < KK; j += 256) {
        float w  = wr[j];
        float ws = w * lns[j];
        if (j < Uu) Wc[(size_t)n * Uu + j] = f2bf(ws);
        else        Wx[(size_t)n * Ii + (j - Uu)] = f2bf(ws);
        s  += ws;
        bb += w * lnb[j];
    }
    float2 tot = block_reduce2(s, bb);
    if (threadIdx.x == 0) { S[n] = tot.x; bias2[n] = bvec[n] + tot.y; }
}

// per-(b,t) row sums of f32 inputs
__global__ __launch_bounds__(256) void k_prep_x(
        const float* __restrict__ X, float2* __restrict__ xsums) {
    size_t row = blockIdx.x;
    const float* xr = X + row * Ii;
    float s = 0.f, s2 = 0.f;
    for (int j = threadIdx.x; j < Ii; j += 256) {
        float v = xr[j];
        s += v; s2 += v * v;
    }
    float2 tot = block_reduce2(s, s2);
    if (threadIdx.x == 0) xsums[row] = tot;
}

// initial carry: resets[:,0] mask, write f32+bf16 state + csums slot 0
__global__ __launch_bounds__(256) void k_prep_c(
        const float* __restrict__ carry, const int* __restrict__ resets,
        float* __restrict__ cf, unsigned short* __restrict__ cb,
        float* __restrict__ csums) {
    int b = blockIdx.x;
    int rr = resets[(size_t)b * Tt];
    float s = 0.f, s2 = 0.f;
    for (int u = threadIdx.x; u < Uu; u += 256) {
        float v = rr ? 0.f : carry[(size_t)b * Uu + u];
        cf[(size_t)b * Uu + u] = v;
        cb[(size_t)b * Uu + u] = f2bf(v);
        s += v; s2 += v * v;
    }
    float2 tot = block_reduce2(s, s2);
    if (threadIdx.x == 0) { csums[2 * b] = tot.x; csums[2 * b + 1] = tot.y; }
}

// convert one T-chunk of X to bf16: xbf[(brow*TC+tc)*Ii + k]
__global__ __launch_bounds__(256) void k_xc(
        const float* __restrict__ X, unsigned short* __restrict__ xbf, int t0) {
    int crow = blockIdx.x;                 // 0..Bb*TC
    int brow = crow >> 7, tc = crow & (TC - 1);
    float4 v = ((const float4*)(X + ((size_t)brow * Tt + t0 + tc) * Ii))[threadIdx.x];
    us4 o;
    o[0] = f2bf(v.x); o[1] = f2bf(v.y); o[2] = f2bf(v.z); o[3] = f2bf(v.w);
    ((us4*)(xbf + (size_t)crow * Ii))[threadIdx.x] = o;
}

// chunk input-half GEMM: Gx[m][n] = sum_k xbf[m][k]*Wx[n][k] (bf16 out)
// block tile 128M x 64N; wave w: M rows {w*16, 64+w*16}, all 64 N.
__global__ __launch_bounds__(256) void k_gx(
        const unsigned short* __restrict__ xbf, const unsigned short* __restrict__ Wx,
        unsigned short* __restrict__ Gx) {
    const int mb = blockIdx.x;            // (Bb*TC)/128
    const int nb = blockIdx.y;            // 48
    const int w = threadIdx.x >> 6, lane = threadIdx.x & 63;
    const int lrow = lane & 15, lkg = lane >> 4;
    const int m1 = mb * 128 + w * 16 + lrow;
    const unsigned short* a1p = xbf + (size_t)m1 * Ii + lkg * 8;
    const unsigned short* a2p = a1p + (size_t)64 * Ii;
    const int n0 = nb * 64;
    const unsigned short* bp0 = Wx + (size_t)(n0 + 0 * 16 + lrow) * Ii + lkg * 8;
    const unsigned short* bp1 = Wx + (size_t)(n0 + 1 * 16 + lrow) * Ii + lkg * 8;
    const unsigned short* bp2 = Wx + (size_t)(n0 + 2 * 16 + lrow) * Ii + lkg * 8;
    const unsigned short* bp3 = Wx + (size_t)(n0 + 3 * 16 + lrow) * Ii + lkg * 8;

    f32x4 acc[2][4] = {{{0,0,0,0},{0,0,0,0},{0,0,0,0},{0,0,0,0}},
                       {{0,0,0,0},{0,0,0,0},{0,0,0,0},{0,0,0,0}}};
    #pragma unroll 4
    for (int k0 = 0; k0 < Ii; k0 += 32) {
        short8 a1 = *(const short8*)(a1p + k0);
        short8 a2 = *(const short8*)(a2p + k0);
        short8 b0 = *(const short8*)(bp0 + k0);
        short8 b1 = *(const short8*)(bp1 + k0);
        short8 b2 = *(const short8*)(bp2 + k0);
        short8 b3 = *(const short8*)(bp3 + k0);
        acc[0][0] = __builtin_amdgcn_mfma_f32_16x16x32_bf16(a1, b0, acc[0][0], 0, 0, 0);
        acc[1][0] = __builtin_amdgcn_mfma_f32_16x16x32_bf16(a2, b0, acc[1][0], 0, 0, 0);
        acc[0][1] = __builtin_amdgcn_mfma_f32_16x16x32_bf16(a1, b1, acc[0][1], 0, 0, 0);
        acc[1][1] = __builtin_amdgcn_mfma_f32_16x16x32_bf16(a2, b1, acc[1][1], 0, 0, 0);
        acc[0][2] = __builtin_amdgcn_mfma_f32_16x16x32_bf16(a1, b2, acc[0][2], 0, 0, 0);
        acc[1][2] = __builtin_amdgcn_mfma_f32_16x16x32_bf16(a2, b2, acc[1][2], 0, 0, 0);
        acc[0][3] = __builtin_amdgcn_mfma_f32_16x16x32_bf16(a1, b3, acc[0][3], 0, 0, 0);
        acc[1][3] = __builtin_amdgcn_mfma_f32_16x16x32_bf16(a2, b3, acc[1][3], 0, 0, 0);
    }
    #pragma unroll
    for (int h = 0; h < 2; ++h) {
        const int mo = mb * 128 + h * 64 + w * 16 + lkg * 4;
        #pragma unroll
        for (int c = 0; c < 4; ++c)
            #pragma unroll
            for (int r = 0; r < 4; ++r)
                Gx[(size_t)(mo + r) * NN + n0 + c * 16 + lrow] = f2bf(acc[h][c][r]);
    }
}

// two-level grid barrier over 256 co-resident blocks.
// bar[g*16] g<16: group counters; bar[256]: root; bar[272]: generation.
__device__ __forceinline__ void gbar(unsigned* bar, unsigned tgt) {
    __syncthreads();                           // drains vmcnt: all block stores done
    if (threadIdx.x == 0) {
        __threadfence();                       // release: L2 writeback to L3
        unsigned g = (unsigned)blockIdx.x >> 4;
        unsigned o = __hip_atomic_fetch_add(&bar[g * 16], 1u, __ATOMIC_RELAXED,
                                            __HIP_MEMORY_SCOPE_AGENT);
        bool fin = false;
        if (o == 15u) {
            unsigned o2 = __hip_atomic_fetch_add(&bar[256], 1u, __ATOMIC_RELAXED,
                                                 __HIP_MEMORY_SCOPE_AGENT);
            if (o2 == 15u) {
                #pragma unroll
                for (int i = 0; i < 16; ++i)
                    __hip_atomic_store(&bar[i * 16], 0u, __ATOMIC_RELAXED,
                                       __HIP_MEMORY_SCOPE_AGENT);
                __hip_atomic_store(&bar[256], 0u, __ATOMIC_RELAXED,
                                   __HIP_MEMORY_SCOPE_AGENT);
                __hip_atomic_store(&bar[272], tgt, __ATOMIC_RELEASE,
                                   __HIP_MEMORY_SCOPE_AGENT);
                fin = true;
            }
        }
        if (!fin) {
            while (__hip_atomic_load(&bar[272], __ATOMIC_RELAXED,
                                     __HIP_MEMORY_SCOPE_AGENT) < tgt)
                __builtin_amdgcn_s_sleep(2);
        }
        __threadfence();                       // acquire: invalidate stale L1/L2
    }
    __syncthreads();
}

// persistent scan over one chunk of TC steps. grid=256 blocks (1/CU), 256 thr.
// block (bt,ut): batch rows bt*16..+16, u-cols ut*16..+16, all 3 gates.
// W slice lives in LDS (swizzled) for the whole chunk; carry blend state in regs.
__global__ __launch_bounds__(256, 1) void k_scan(
        int t0,
        const unsigned short* __restrict__ Gx,
        const unsigned short* __restrict__ Wc,
        const float* __restrict__ Sv,
        const float* __restrict__ bias2,
        const float2* __restrict__ xsums,
        const int* __restrict__ resets,
        float* __restrict__ cf,
        unsigned short* __restrict__ cb,      // [2][Bb][Uu]
        float* __restrict__ csums,            // [Tt+1][Bb][2]
        float* __restrict__ out,
        unsigned* __restrict__ bar) {
    __shared__ unsigned short Wl[48 * 1024];  // 96 KiB, XOR-swizzled
    __shared__ float red[4 * 64 * 13];        // 13 KiB cross-wave reduce

    const int ut = blockIdx.x & 63, bt = blockIdx.x >> 6;
    const int w = threadIdx.x >> 6, lane = threadIdx.x & 63;
    const int lrow = lane & 15, lkg = lane >> 4;

    // ---- W slice -> LDS, swizzle byte ^= ((row&7)<<4) within 2 KiB rows ----
    for (int c = threadIdx.x; c < 48 * 128; c += 256) {
        int row = c >> 7, kc = c & 127;       // row in [0,48), 16B chunk in row
        int g = row >> 4, rr = row & 15;
        short8 v = *(const short8*)(Wc + (((size_t)g * Uu + ut * 16 + rr) << 10) + (kc << 3));
        unsigned byte = ((unsigned)row << 11) | ((((unsigned)kc << 4) ^ (((unsigned)row & 7) << 4)));
        *(short8*)((char*)Wl + byte) = v;
    }

    // ---- fixed per-thread constants ----
    const int u    = ut * 16 + lrow;              // output column
    const int brow = bt * 16 + lkg * 4 + w;       // output batch row (r=w trick)
    const float S0 = Sv[u],      S1 = Sv[Uu + u],      S2 = Sv[2 * Uu + u];
    const float B0 = bias2[u],   B1 = bias2[Uu + u],   B2 = bias2[2 * Uu + u];
    float cold = cf[(size_t)brow * Uu + u];       // masked carry, register-resident

    const int arow = bt * 16 + lrow;              // A-fragment batch row
    const unsigned swz = ((unsigned)lrow & 7) << 4;
    const unsigned wb0 = ((unsigned)(0 * 16 + lrow)) << 11;
    const unsigned wb1 = ((unsigned)(1 * 16 + lrow)) << 11;
    const unsigned wb2 = ((unsigned)(2 * 16 + lrow)) << 11;
    const unsigned kbase = (unsigned)w * 512 + (unsigned)lkg * 16;  // K byte offset

    __syncthreads();

    for (int tc = 0; tc < TC; ++tc) {
        const int t = t0 + tc;
        const bool lastg = (t == Tt - 1);
        const unsigned short* cbc = cb + ((size_t)(t & 1)) * Bb * Uu;
        const unsigned short* ap = cbc + (size_t)arow * Uu + (w * 256 + lkg * 8);

        // A loads (global, post-barrier fresh from L3)
        short8 av[8];
        #pragma unroll
        for (int i = 0; i < 8; ++i) av[i] = *(const short8*)(ap + i * 32);

        // epilogue operand stream (issued early, hidden under GEMM)
        const unsigned short* gp = Gx + ((size_t)brow * TC + tc) * NN;
        unsigned short g0r = gp[u], g1r = gp[Uu + u], g2r = gp[2 * Uu + u];
        float2 xsv = xsums[(size_t)brow * Tt + t];
        float csx = __hip_atomic_load(&csums[2 * ((size_t)t * Bb + brow)],
                                      __ATOMIC_RELAXED, __HIP_MEMORY_SCOPE_AGENT);
        float csy = __hip_atomic_load(&csums[2 * ((size_t)t * Bb + brow) + 1],
                                      __ATOMIC_RELAXED, __HIP_MEMORY_SCOPE_AGENT);
        int rrn = lastg ? 1 : resets[(size_t)brow * Tt + (t + 1)];

        // K-split GEMM: wave w covers K elems [w*256, w*256+256)
        f32x4 acc0 = {0.f, 0.f, 0.f, 0.f};
        f32x4 acc1 = acc0, acc2 = acc0;
        #pragma unroll
        for (int i = 0; i < 8; ++i) {
            unsigned ko = (kbase + (unsigned)(i * 64)) ^ swz;
            short8 w0 = *(const short8*)((const char*)Wl + (wb0 + ko));
            short8 w1 = *(const short8*)((const char*)Wl + (wb1 + ko));
            short8 w2 = *(const short8*)((const char*)Wl + (wb2 + ko));
            acc0 = __builtin_amdgcn_mfma_f32_16x16x32_bf16(av[i], w0, acc0, 0, 0, 0);
            acc1 = __builtin_amdgcn_mfma_f32_16x16x32_bf16(av[i], w1, acc1, 0, 0, 0);
            acc2 = __builtin_amdgcn_mfma_f32_16x16x32_bf16(av[i], w2, acc2, 0, 0, 0);
        }

        // cross-wave K reduction (thread takes acc element r=w at its lane)
        float* rp = red + (w * 64 + lane) * 13;
        #pragma unroll
        for (int r = 0; r < 4; ++r) {
            rp[r] = acc0[r]; rp[4 + r] = acc1[r]; rp[8 + r] = acc2[r];
        }
        __syncthreads();
        float y0 = 0.f, y1 = 0.f, y2 = 0.f;
        #pragma unroll
        for (int w2 = 0; w2 < 4; ++w2) {
            const float* q = red + (w2 * 64 + lane) * 13;
            y0 += q[w]; y1 += q[4 + w]; y2 += q[8 + w];
        }

        // LN-linearized epilogue + gates
        float mu  = (csx + xsv.x) * (1.f / (float)KK);
        float var = (csy + xsv.y) * (1.f / (float)KK) - mu * mu;
        float rs  = rsqrtf(var + 1e-3f);
        float mrs = mu * rs;
        float yr = rs * (y0 + bf2f(g0r)) - mrs * S0 + B0;
        float yc = rs * (y1 + bf2f(g1r)) - mrs * S1 + B1;
        float yu = rs * (y2 + bf2f(g2r)) - mrs * S2 + B2;
        float sres = 1.f / (1.f + expf(-yr));
        float cand = tanhf(sres * yc);
        float updv = 1.f / (1.f + expf(-(yu - 1.f)));
        float cnew = updv * cand + (1.f - updv) * cold;

        out[(size_t)Bb * Uu + ((size_t)brow * Tt + t) * Uu + u] = cnew;
        if (lastg) out[(size_t)brow * Uu + u] = cnew;

        float cm = (lastg || rrn) ? 0.f : cnew;
        if (!lastg) {
            unsigned short* cbn = cb + ((size_t)((t + 1) & 1)) * Bb * Uu;
            cbn[(size_t)brow * Uu + u] = f2bf(cm);
        }
        cold = cm;

        float s = cm, s2 = cm * cm;
        #pragma unroll
        for (int m = 1; m < 16; m <<= 1) {
            s  += __shfl_xor(s,  m, 16);
            s2 += __shfl_xor(s2, m, 16);
        }
        if (!lastg && lrow == 0) {
            atomicAdd(&csums[2 * ((size_t)(t + 1) * Bb + brow)],     s);
            atomicAdd(&csums[2 * ((size_t)(t + 1) * Bb + brow) + 1], s2);
        }

        if (tc == TC - 1) cf[(size_t)brow * Uu + u] = cold;   // chunk handoff
        else              gbar(bar, (unsigned)(tc + 1));
    }
}

extern "C" void kernel_launch(void* const* d_in, const int* in_sizes, int n_in,
                              void* d_out, int out_size, void* d_ws, size_t ws_size,
                              hipStream_t stream) {
    const float* carry  = (const float*)d_in[0];
    const float* inputs = (const float*)d_in[1];
    const int*   resets = (const int*)d_in[2];
    const float* W      = (const float*)d_in[3];
    const float* bvec   = (const float*)d_in[4];
    const float* lns    = (const float*)d_in[5];
    const float* lnb    = (const float*)d_in[6];
    float* out = (float*)d_out;

    char* ws = (char*)d_ws;
    size_t off = 0;
    auto alloc = [&](size_t bytes) -> void* {
        void* p = ws + off;
        off += (bytes + 255) & ~(size_t)255;
        return p;
    };
    unsigned short* Wc    = (unsigned short*)alloc((size_t)NN * Uu * 2);
    unsigned short* Wx    = (unsigned short*)alloc((size_t)NN * Ii * 2);
    float*          S     = (float*)alloc((size_t)NN * 4);
    float*          bias2 = (float*)alloc((size_t)NN * 4);
    float2*         xsums = (float2*)alloc((size_t)Bb * Tt * 8);
    float*          cf    = (float*)alloc((size_t)Bb * Uu * 4);
    unsigned short* cb    = (unsigned short*)alloc((size_t)2 * Bb * Uu * 2);
    float*          csums = (float*)alloc((size_t)(Tt + 1) * Bb * 2 * 4);
    unsigned*       bar   = (unsigned*)alloc(2048);
    unsigned short* xbf   = (unsigned short*)alloc((size_t)Bb * TC * Ii * 2);   // 16.8 MB
    unsigned short* Gx    = (unsigned short*)alloc((size_t)Bb * TC * NN * 2);   // 50.3 MB
    // total ~80.8 MB <= round-1-proven ws floor (~81.0 MB)

    hipMemsetAsync(csums, 0, (size_t)(Tt + 1) * Bb * 2 * 4, stream);

    k_prep_w<<<NN, 256, 0, stream>>>(W, bvec, lns, lnb, Wc, Wx, S, bias2);
    k_prep_x<<<Bb * Tt, 256, 0, stream>>>(inputs, xsums);
    k_prep_c<<<Bb, 256, 0, stream>>>(carry, resets, cf, cb, csums);

    for (int chunk = 0; chunk < NCHUNK; ++chunk) {
        int t0 = chunk * TC;
        k_xc<<<Bb * TC, 256, 0, stream>>>(inputs, xbf, t0);
        k_gx<<<dim3((Bb * TC) / 128, NN / 64), 256, 0, stream>>>(xbf, Wx, Gx);
        hipMemsetAsync(bar, 0, 2048, stream);
        k_scan<<<NBLK, 256, 0, stream>>>(t0, Gx, Wc, S, bias2, xsums, resets,
                                         cf, cb, csums, out, bar);
    }
}

// Round 4
// 5015.866 us; speedup vs baseline: 2.5693x; 2.5693x over previous
//
#include <hip/hip_runtime.h>
#include <stdint.h>

#define Bb 64
#define Tt 512
#define Ii 1024
#define Uu 1024
#define KK 2048
#define NN 3072
#define TC 128            // scan chunk length
#define NCHUNK 4
#define NBLK 256

typedef __attribute__((ext_vector_type(8))) short short8;
typedef __attribute__((ext_vector_type(4))) float f32x4;
typedef __attribute__((ext_vector_type(4))) unsigned short us4;

__device__ __forceinline__ unsigned short f2bf(float f) {
    union { float f; unsigned u; } v; v.f = f;
    return (unsigned short)((v.u + 0x7FFFu + ((v.u >> 16) & 1u)) >> 16);
}
__device__ __forceinline__ float bf2f(unsigned short h) {
    union { unsigned u; float f; } v; v.u = ((unsigned)h) << 16;
    return v.f;
}

__device__ __forceinline__ float2 block_reduce2(float s, float s2) {
    int lane = threadIdx.x & 63, wv = threadIdx.x >> 6;
    #pragma unroll
    for (int m = 32; m > 0; m >>= 1) {
        s  += __shfl_down(s,  m, 64);
        s2 += __shfl_down(s2, m, 64);
    }
    __shared__ float sh[4][2];
    if (lane == 0) { sh[wv][0] = s; sh[wv][1] = s2; }
    __syncthreads();
    float a = 0.f, b = 0.f;
    if (threadIdx.x == 0) {
        #pragma unroll
        for (int i = 0; i < 4; ++i) { a += sh[i][0]; b += sh[i][1]; }
    }
    return make_float2(a, b);
}

// W (3072x2048 f32) -> Wc, Wx (bf16, LN-scale folded), S_n, bias2_n
__global__ __launch_bounds__(256) void k_prep_w(
        const float* __restrict__ W, const float* __restrict__ bvec,
        const float* __restrict__ lns, const float* __restrict__ lnb,
        unsigned short* __restrict__ Wc, unsigned short* __restrict__ Wx,
        float* __restrict__ S, float* __restrict__ bias2) {
    int n = blockIdx.x;
    const float* wr = W + (size_t)n * KK;
    float s = 0.f, bb = 0.f;
    for (int j = threadIdx.x; j < KK; j += 256) {
        float w  = wr[j];
        float ws = w * lns[j];
        if (j < Uu) Wc[(size_t)n * Uu + j] = f2bf(ws);
        else        Wx[(size_t)n * Ii + (j - Uu)] = f2bf(ws);
        s  += ws;
        bb += w * lnb[j];
    }
    float2 tot = block_reduce2(s, bb);
    if (threadIdx.x == 0) { S[n] = tot.x; bias2[n] = bvec[n] + tot.y; }
}

// per-(b,t) row sums of f32 inputs
__global__ __launch_bounds__(256) void k_prep_x(
        const float* __restrict__ X, float2* __restrict__ xsums) {
    size_t row = blockIdx.x;
    const float* xr = X + row * Ii;
    float s = 0.f, s2 = 0.f;
    for (int j = threadIdx.x; j < Ii; j += 256) {
        float v = xr[j];
        s += v; s2 += v * v;
    }
    float2 tot = block_reduce2(s, s2);
    if (threadIdx.x == 0) xsums[row] = tot;
}

// initial carry: resets[:,0] mask, write f32+bf16 state
__global__ __launch_bounds__(256) void k_prep_c(
        const float* __restrict__ carry, const int* __restrict__ resets,
        float* __restrict__ cf, unsigned short* __restrict__ cb) {
    int b = blockIdx.x;
    int rr = resets[(size_t)b * Tt];
    for (int u = threadIdx.x; u < Uu; u += 256) {
        float v = rr ? 0.f : carry[(size_t)b * Uu + u];
        cf[(size_t)b * Uu + u] = v;
        cb[(size_t)b * Uu + u] = f2bf(v);
    }
}

// convert one T-chunk of X to bf16: xbf[(brow*TC+tc)*Ii + k]
__global__ __launch_bounds__(256) void k_xc(
        const float* __restrict__ X, unsigned short* __restrict__ xbf, int t0) {
    int crow = blockIdx.x;                 // 0..Bb*TC
    int brow = crow >> 7, tc = crow & (TC - 1);
    float4 v = ((const float4*)(X + ((size_t)brow * Tt + t0 + tc) * Ii))[threadIdx.x];
    us4 o;
    o[0] = f2bf(v.x); o[1] = f2bf(v.y); o[2] = f2bf(v.z); o[3] = f2bf(v.w);
    ((us4*)(xbf + (size_t)crow * Ii))[threadIdx.x] = o;
}

// chunk input-half GEMM: Gx[m][n] = sum_k xbf[m][k]*Wx[n][k] (bf16 out)
__global__ __launch_bounds__(256) void k_gx(
        const unsigned short* __restrict__ xbf, const unsigned short* __restrict__ Wx,
        unsigned short* __restrict__ Gx) {
    const int mb = blockIdx.x;            // (Bb*TC)/128
    const int nb = blockIdx.y;            // 48
    const int w = threadIdx.x >> 6, lane = threadIdx.x & 63;
    const int lrow = lane & 15, lkg = lane >> 4;
    const int m1 = mb * 128 + w * 16 + lrow;
    const unsigned short* a1p = xbf + (size_t)m1 * Ii + lkg * 8;
    const unsigned short* a2p = a1p + (size_t)64 * Ii;
    const int n0 = nb * 64;
    const unsigned short* bp0 = Wx + (size_t)(n0 + 0 * 16 + lrow) * Ii + lkg * 8;
    const unsigned short* bp1 = Wx + (size_t)(n0 + 1 * 16 + lrow) * Ii + lkg * 8;
    const unsigned short* bp2 = Wx + (size_t)(n0 + 2 * 16 + lrow) * Ii + lkg * 8;
    const unsigned short* bp3 = Wx + (size_t)(n0 + 3 * 16 + lrow) * Ii + lkg * 8;

    f32x4 acc[2][4] = {{{0,0,0,0},{0,0,0,0},{0,0,0,0},{0,0,0,0}},
                       {{0,0,0,0},{0,0,0,0},{0,0,0,0},{0,0,0,0}}};
    #pragma unroll 4
    for (int k0 = 0; k0 < Ii; k0 += 32) {
        short8 a1 = *(const short8*)(a1p + k0);
        short8 a2 = *(const short8*)(a2p + k0);
        short8 b0 = *(const short8*)(bp0 + k0);
        short8 b1 = *(const short8*)(bp1 + k0);
        short8 b2 = *(const short8*)(bp2 + k0);
        short8 b3 = *(const short8*)(bp3 + k0);
        acc[0][0] = __builtin_amdgcn_mfma_f32_16x16x32_bf16(a1, b0, acc[0][0], 0, 0, 0);
        acc[1][0] = __builtin_amdgcn_mfma_f32_16x16x32_bf16(a2, b0, acc[1][0], 0, 0, 0);
        acc[0][1] = __builtin_amdgcn_mfma_f32_16x16x32_bf16(a1, b1, acc[0][1], 0, 0, 0);
        acc[1][1] = __builtin_amdgcn_mfma_f32_16x16x32_bf16(a2, b1, acc[1][1], 0, 0, 0);
        acc[0][2] = __builtin_amdgcn_mfma_f32_16x16x32_bf16(a1, b2, acc[0][2], 0, 0, 0);
        acc[1][2] = __builtin_amdgcn_mfma_f32_16x16x32_bf16(a2, b2, acc[1][2], 0, 0, 0);
        acc[0][3] = __builtin_amdgcn_mfma_f32_16x16x32_bf16(a1, b3, acc[0][3], 0, 0, 0);
        acc[1][3] = __builtin_amdgcn_mfma_f32_16x16x32_bf16(a2, b3, acc[1][3], 0, 0, 0);
    }
    #pragma unroll
    for (int h = 0; h < 2; ++h) {
        const int mo = mb * 128 + h * 64 + w * 16 + lkg * 4;
        #pragma unroll
        for (int c = 0; c < 4; ++c)
            #pragma unroll
            for (int r = 0; r < 4; ++r)
                Gx[(size_t)(mo + r) * NN + n0 + c * 16 + lrow] = f2bf(acc[h][c][r]);
    }
}

// Fence-free grid barrier: all cross-block data moves via agent-scope atomics,
// so the barrier needs only control sync. Monotonic counters (no reset race).
__device__ __forceinline__ void gbar(unsigned* bar, unsigned tgt) {
    __syncthreads();   // each wave drains its own vmcnt before s_barrier
    if (threadIdx.x == 0) {
        unsigned g = (unsigned)blockIdx.x >> 4;
        unsigned o = __hip_atomic_fetch_add(&bar[g * 16], 1u, __ATOMIC_RELAXED,
                                            __HIP_MEMORY_SCOPE_AGENT) + 1u;
        bool pub = false;
        if (o == tgt * 16u) {
            unsigned o2 = __hip_atomic_fetch_add(&bar[256], 1u, __ATOMIC_RELAXED,
                                                 __HIP_MEMORY_SCOPE_AGENT) + 1u;
            if (o2 == tgt * 16u) {
                __hip_atomic_store(&bar[272], tgt, __ATOMIC_RELAXED,
                                   __HIP_MEMORY_SCOPE_AGENT);
                pub = true;
            }
        }
        if (!pub) {
            while (__hip_atomic_load(&bar[272], __ATOMIC_RELAXED,
                                     __HIP_MEMORY_SCOPE_AGENT) < tgt)
                __builtin_amdgcn_s_sleep(2);
        }
    }
    __syncthreads();
}

// persistent scan over one chunk of TC steps. grid=256 blocks (1/CU), 256 thr.
// block (bt,ut): batch rows bt*16..+16, u-cols ut*16..+16, all 3 gates.
// W slice in LDS for the whole chunk; carry exchanged via coherent 8B atomics;
// LN sums computed locally from the A operand via 2 extra MFMA chains.
__global__ __launch_bounds__(256, 1) void k_scan(
        int t0,
        const unsigned short* __restrict__ Gx,
        const unsigned short* __restrict__ Wc,
        const float* __restrict__ Sv,
        const float* __restrict__ bias2,
        const float2* __restrict__ xsums,
        const int* __restrict__ resets,
        float* __restrict__ cf,
        unsigned long long* __restrict__ cb,  // [2][Bb][Uu/4] as 8B words
        float* __restrict__ out,
        unsigned* __restrict__ bar) {
    __shared__ unsigned short Wl[48 * 1024];   // 96 KiB, XOR-swizzled
    __shared__ float red[4 * 64 * 13];         // 13 KiB cross-wave K reduce
    __shared__ float sums_sh[4][16][2];        // per-wave carry row sums
    __shared__ unsigned short cpack[16][16];   // new-carry pack tile

    const int ut = blockIdx.x & 63, bt = blockIdx.x >> 6;
    const int w = threadIdx.x >> 6, lane = threadIdx.x & 63;
    const int lrow = lane & 15, lkg = lane >> 4;

    // ---- W slice -> LDS, swizzle byte ^= ((row&7)<<4) within 2 KiB rows ----
    for (int c = threadIdx.x; c < 48 * 128; c += 256) {
        int row = c >> 7, kc = c & 127;
        int g = row >> 4, rr = row & 15;
        short8 v = *(const short8*)(Wc + (((size_t)g * Uu + ut * 16 + rr) << 10) + (kc << 3));
        unsigned byte = ((unsigned)row << 11) | ((((unsigned)kc << 4) ^ (((unsigned)row & 7) << 4)));
        *(short8*)((char*)Wl + byte) = v;
    }

    // ---- fixed per-thread constants ----
    const int u    = ut * 16 + lrow;              // output column
    const int erow = lkg * 4 + w;                 // row within batch tile (epilogue)
    const int brow = bt * 16 + erow;              // output batch row
    const float S0 = Sv[u],      S1 = Sv[Uu + u],      S2 = Sv[2 * Uu + u];
    const float B0 = bias2[u],   B1 = bias2[Uu + u],   B2 = bias2[2 * Uu + u];
    float cold = cf[(size_t)brow * Uu + u];       // masked carry, register-resident

    const int arow = bt * 16 + lrow;              // A-fragment batch row
    const unsigned swz = ((unsigned)lrow & 7) << 4;
    const unsigned wb0 = ((unsigned)(0 * 16 + lrow)) << 11;
    const unsigned wb1 = ((unsigned)(1 * 16 + lrow)) << 11;
    const unsigned wb2 = ((unsigned)(2 * 16 + lrow)) << 11;
    const unsigned kbase = (unsigned)w * 512 + (unsigned)lkg * 16;  // K byte offset

    short8 ones;
    #pragma unroll
    for (int j = 0; j < 8; ++j) ones[j] = (short)0x3F80;   // bf16 1.0

    // A-load base (8B words): row arow, elems w*256 + lkg*8 + i*32
    const unsigned long long* apb = cb + ((size_t)arow * Uu + (w * 256 + lkg * 8)) / 4;

    __syncthreads();

    for (int tc = 0; tc < TC; ++tc) {
        const int t = t0 + tc;
        const bool lastg = (t == Tt - 1);
        const unsigned long long* ap = apb + ((size_t)(t & 1)) * (Bb * Uu / 4);

        // ---- coherent A loads (L2-bypassing, straight from coherence point) ----
        short8 av[8];
        #pragma unroll
        for (int i = 0; i < 8; ++i) {
            union { unsigned long long q[2]; short8 v; } uu;
            uu.q[0] = __hip_atomic_load(ap + i * 8,     __ATOMIC_RELAXED, __HIP_MEMORY_SCOPE_AGENT);
            uu.q[1] = __hip_atomic_load(ap + i * 8 + 1, __ATOMIC_RELAXED, __HIP_MEMORY_SCOPE_AGENT);
            av[i] = uu.v;
        }

        // epilogue operand stream (read-only, L2-warm)
        const unsigned short* gp = Gx + ((size_t)brow * TC + tc) * NN;
        unsigned short g0r = gp[u], g1r = gp[Uu + u], g2r = gp[2 * Uu + u];
        float2 xsv = xsums[(size_t)brow * Tt + t];
        int rrn = lastg ? 1 : resets[(size_t)brow * Tt + (t + 1)];

        // ---- GEMM + carry-sum MFMAs: wave w covers K elems [w*256, +256) ----
        f32x4 acc0 = {0.f, 0.f, 0.f, 0.f};
        f32x4 acc1 = acc0, acc2 = acc0, accS = acc0, accQ = acc0;
        #pragma unroll
        for (int i = 0; i < 8; ++i) {
            unsigned ko = (kbase + (unsigned)(i * 64)) ^ swz;
            short8 w0 = *(const short8*)((const char*)Wl + (wb0 + ko));
            short8 w1 = *(const short8*)((const char*)Wl + (wb1 + ko));
            short8 w2 = *(const short8*)((const char*)Wl + (wb2 + ko));
            acc0 = __builtin_amdgcn_mfma_f32_16x16x32_bf16(av[i], w0, acc0, 0, 0, 0);
            acc1 = __builtin_amdgcn_mfma_f32_16x16x32_bf16(av[i], w1, acc1, 0, 0, 0);
            acc2 = __builtin_amdgcn_mfma_f32_16x16x32_bf16(av[i], w2, acc2, 0, 0, 0);
            accS = __builtin_amdgcn_mfma_f32_16x16x32_bf16(av[i], ones,  accS, 0, 0, 0);
            accQ = __builtin_amdgcn_mfma_f32_16x16x32_bf16(av[i], av[i], accQ, 0, 0, 0);
        }

        // ---- cross-wave K reduction + local LN sums ----
        float* rp = red + (w * 64 + lane) * 13;
        #pragma unroll
        for (int r = 0; r < 4; ++r) {
            rp[r] = acc0[r]; rp[4 + r] = acc1[r]; rp[8 + r] = acc2[r];
        }
        if (lkg == (lrow >> 2)) {                 // diag holders: row==col==lrow
            sums_sh[w][lrow][0] = accS[lrow & 3];
            sums_sh[w][lrow][1] = accQ[lrow & 3];
        }
        __syncthreads();
        float y0 = 0.f, y1 = 0.f, y2 = 0.f, csx = 0.f, csy = 0.f;
        #pragma unroll
        for (int w2 = 0; w2 < 4; ++w2) {
            const float* q = red + (w2 * 64 + lane) * 13;
            y0 += q[w]; y1 += q[4 + w]; y2 += q[8 + w];
            csx += sums_sh[w2][erow][0];
            csy += sums_sh[w2][erow][1];
        }

        // ---- LN-linearized epilogue + gates ----
        float mu  = (csx + xsv.x) * (1.f / (float)KK);
        float var = (csy + xsv.y) * (1.f / (float)KK) - mu * mu;
        float rs  = rsqrtf(var + 1e-3f);
        float mrs = mu * rs;
        float yr = rs * (y0 + bf2f(g0r)) - mrs * S0 + B0;
        float yc = rs * (y1 + bf2f(g1r)) - mrs * S1 + B1;
        float yu = rs * (y2 + bf2f(g2r)) - mrs * S2 + B2;
        float sres = 1.f / (1.f + expf(-yr));
        float cand = tanhf(sres * yc);
        float updv = 1.f / (1.f + expf(-(yu - 1.f)));
        float cnew = updv * cand + (1.f - updv) * cold;

        out[(size_t)Bb * Uu + ((size_t)brow * Tt + t) * Uu + u] = cnew;
        if (lastg) out[(size_t)brow * Uu + u] = cnew;

        float cm = (lastg || rrn) ? 0.f : cnew;
        cpack[erow][lrow] = f2bf(cm);
        cold = cm;

        if (tc == TC - 1) {
            cf[(size_t)brow * Uu + u] = cold;     // chunk handoff (f32)
            if (!lastg) {                          // bf16 handoff for next chunk
                __syncthreads();
                if (w == 0) {
                    int r = lane >> 2, c4 = (lane & 3) * 4;
                    union { unsigned long long q; us4 s; } pk;
                    pk.s = *(const us4*)&cpack[r][c4];
                    unsigned long long* dst = cb + ((size_t)((t + 1) & 1)) * (Bb * Uu / 4)
                                            + ((size_t)(bt * 16 + r) * Uu + ut * 16 + c4) / 4;
                    __hip_atomic_store(dst, pk.q, __ATOMIC_RELAXED, __HIP_MEMORY_SCOPE_AGENT);
                }
            }
        } else {
            __syncthreads();                       // cpack visible
            if (w == 0) {                          // 64 coherent 8B stores
                int r = lane >> 2, c4 = (lane & 3) * 4;
                union { unsigned long long q; us4 s; } pk;
                pk.s = *(const us4*)&cpack[r][c4];
                unsigned long long* dst = cb + ((size_t)((t + 1) & 1)) * (Bb * Uu / 4)
                                        + ((size_t)(bt * 16 + r) * Uu + ut * 16 + c4) / 4;
                __hip_atomic_store(dst, pk.q, __ATOMIC_RELAXED, __HIP_MEMORY_SCOPE_AGENT);
            }
            gbar(bar, (unsigned)(tc + 1));         // syncthreads drains the stores
        }
    }
}

extern "C" void kernel_launch(void* const* d_in, const int* in_sizes, int n_in,
                              void* d_out, int out_size, void* d_ws, size_t ws_size,
                              hipStream_t stream) {
    const float* carry  = (const float*)d_in[0];
    const float* inputs = (const float*)d_in[1];
    const int*   resets = (const int*)d_in[2];
    const float* W      = (const float*)d_in[3];
    const float* bvec   = (const float*)d_in[4];
    const float* lns    = (const float*)d_in[5];
    const float* lnb    = (const float*)d_in[6];
    float* out = (float*)d_out;

    char* ws = (char*)d_ws;
    size_t off = 0;
    auto alloc = [&](size_t bytes) -> void* {
        void* p = ws + off;
        off += (bytes + 255) & ~(size_t)255;
        return p;
    };
    unsigned short*     Wc    = (unsigned short*)alloc((size_t)NN * Uu * 2);
    unsigned short*     Wx    = (unsigned short*)alloc((size_t)NN * Ii * 2);
    float*              S     = (float*)alloc((size_t)NN * 4);
    float*              bias2 = (float*)alloc((size_t)NN * 4);
    float2*             xsums = (float2*)alloc((size_t)Bb * Tt * 8);
    float*              cf    = (float*)alloc((size_t)Bb * Uu * 4);
    unsigned long long* cb    = (unsigned long long*)alloc((size_t)2 * Bb * Uu * 2);
    unsigned*           bar   = (unsigned*)alloc(2048);
    unsigned short*     xbf   = (unsigned short*)alloc((size_t)Bb * TC * Ii * 2);   // 16.8 MB
    unsigned short*     Gx    = (unsigned short*)alloc((size_t)Bb * TC * NN * 2);   // 50.3 MB

    k_prep_w<<<NN, 256, 0, stream>>>(W, bvec, lns, lnb, Wc, Wx, S, bias2);
    k_prep_x<<<Bb * Tt, 256, 0, stream>>>(inputs, xsums);
    k_prep_c<<<Bb, 256, 0, stream>>>(carry, resets, cf, (unsigned short*)cb);

    for (int chunk = 0; chunk < NCHUNK; ++chunk) {
        int t0 = chunk * TC;
        k_xc<<<Bb * TC, 256, 0, stream>>>(inputs, xbf, t0);
        k_gx<<<dim3((Bb * TC) / 128, NN / 64), 256, 0, stream>>>(xbf, Wx, Gx);
        hipMemsetAsync(bar, 0, 2048, stream);
        k_scan<<<NBLK, 256, 0, stream>>>(t0, Gx, Wc, S, bias2, xsums, resets,
                                         cf, cb, out, bar);
    }
}